// Round 6
// baseline (74.992 us; speedup 1.0000x reference)
//
#include <hip/hip_runtime.h>

#define NHEADS 8
#define NN     128
#define NCELL  (NN * NN)       // 16384 floats = 64 KiB
#define NT     512             // 8 waves
#define SCALE_F 10.0f

typedef float nfloat4 __attribute__((ext_vector_type(4)));

// Blocked Floyd-Warshall, B=16, one block (512 thr) per graph.
// Thread t: rgrp=t>>4 (rows 4rgrp..+4), cgrp=t&15 (cols 4cgrp+64c+e, c=0..1).
// dd[4][8] register-resident.
// Pipelined step schedule (A off the critical path):
//   prep(0); bar; for kb: { B(kb); bar; C(kb); prep(kb+1); bar }
// prep(kbn) = wave kbn extracts its rows -> RP_O, dumps diag -> DP,
// runs in-register readlane closure, publishes D*/D*T; col-owners (all
// waves) extract -> CP_O. Runs while other waves drain C's LDS traffic.
//
// LDS float offsets (panels swizzled: elem(row,j) at row*128+4*((j>>2)^(row&7))+(j&3)):
#define RP_O 0
#define RP_N 2048
#define CP_O 4096
#define CP_N 6144
#define DP   8192     // D* [16][16]  (DP[x*16+y] = D*[x][y])
#define DPT  8448     // D*T          (DPT[x*16+y] = D*[y][x])
#define RED  8704

template<int CBN>   // CBN = 4*(kbn>>2): dd column-half holding block kbn's cols
__device__ __forceinline__ void prep_next(float (&dd)[4][8], float* lds,
                                          const int kbn, const int t,
                                          const int rgrp, const int cgrp)
{
    // ---- wave kbn: extract row panel, dump diag tile, closure ----
    if ((t >> 6) == kbn) {
        const int q = rgrp & 3;
        #pragma unroll
        for (int rr = 0; rr < 4; ++rr) {
            const int iloc = 4 * q + rr;
            const int sw = iloc & 7;
            #pragma unroll
            for (int c = 0; c < 2; ++c) {
                *reinterpret_cast<float4*>(
                    &lds[RP_O + iloc*128 + (((cgrp + 16*c) ^ sw) << 2)]) =
                    make_float4(dd[rr][c*4+0], dd[rr][c*4+1],
                                dd[rr][c*4+2], dd[rr][c*4+3]);
            }
        }
        const int l = t & 63;
        const int p = (cgrp - 4 * (kbn & 3)) & 15;
        if (p < 4) {                        // diag-tile owner (16 thr of wave kbn)
            #pragma unroll
            for (int rr = 0; rr < 4; ++rr) {
                *reinterpret_cast<float4*>(&lds[DP + (4*q+rr)*16 + 4*p]) =
                    make_float4(dd[rr][CBN+0], dd[rr][CBN+1],
                                dd[rr][CBN+2], dd[rr][CBN+3]);
            }
        }
        asm volatile("s_waitcnt lgkmcnt(0)" ::: "memory");
        float T[16];
        const int lr = l & 15;              // each lane: row lr (4x duplicated)
        #pragma unroll
        for (int c4 = 0; c4 < 4; ++c4) {
            float4 v = *reinterpret_cast<const float4*>(&lds[DP + lr*16 + 4*c4]);
            T[c4*4+0]=v.x; T[c4*4+1]=v.y; T[c4*4+2]=v.z; T[c4*4+3]=v.w;
        }
        #pragma unroll
        for (int k = 0; k < 16; ++k) {
            float rk[16];
            #pragma unroll
            for (int j = 0; j < 16; ++j)
                rk[j] = __int_as_float(
                    __builtin_amdgcn_readlane(__float_as_int(T[j]), k));
            const float dik = T[k];
            #pragma unroll
            for (int j = 0; j < 16; ++j)
                T[j] = fminf(T[j], dik + rk[j]);
        }
        if (l < 16) {                       // publish D* and D*T
            #pragma unroll
            for (int c4 = 0; c4 < 4; ++c4)
                *reinterpret_cast<float4*>(&lds[DP + l*16 + 4*c4]) =
                    make_float4(T[c4*4], T[c4*4+1], T[c4*4+2], T[c4*4+3]);
            #pragma unroll
            for (int j = 0; j < 16; ++j)
                lds[DPT + j*16 + l] = T[j];
        }
    }
    // ---- col-panel extract (owners spread over all waves) ----
    {
        const int q2 = (cgrp - 4 * kbn) & 15;
        if (q2 < 4) {
            #pragma unroll
            for (int e = 0; e < 4; ++e) {
                const int jj = 4 * q2 + e;
                *reinterpret_cast<float4*>(
                    &lds[CP_O + jj*128 + ((rgrp ^ (jj & 7)) << 2)]) =
                    make_float4(dd[0][CBN+e], dd[1][CBN+e],
                                dd[2][CBN+e], dd[3][CBN+e]);
            }
        }
    }
}

// phase B: R_new = D* (x) R_old ; C_newT = D*T (x) C_oldT.
// 256 threads: (isC = t>>7, a2 = (t>>5)&3 -> rows 4a2..+3, ch = t&31).
// Per k: one broadcast float4 of D* + one float4 of panel row k.
__device__ __forceinline__ void phaseB(float* lds, const int t)
{
    if (t < 256) {
        const float INF = __builtin_huge_valf();
        const int ch   = t & 31;
        const int a2   = (t >> 5) & 3;
        const int isC  = t >> 7;
        const int pbase = isC ? CP_O : RP_O;
        const int dbase = isC ? DP   : DPT;  // R: D*[a][k]=DPT[k][a]; C: D*[k][a]=DP[k][a]
        const int obase = isC ? CP_N : RP_N;
        float acc[4][4];
        #pragma unroll
        for (int rr = 0; rr < 4; ++rr)
            #pragma unroll
            for (int e = 0; e < 4; ++e) acc[rr][e] = INF;
        #pragma unroll
        for (int k = 0; k < 16; ++k) {
            float4 dt = *reinterpret_cast<const float4*>(&lds[dbase + k*16 + 4*a2]);
            float4 r  = *reinterpret_cast<const float4*>(
                &lds[pbase + k*128 + ((ch ^ (k & 7)) << 2)]);
            const float d[4] = {dt.x, dt.y, dt.z, dt.w};
            const float rv[4] = {r.x, r.y, r.z, r.w};
            #pragma unroll
            for (int rr = 0; rr < 4; ++rr)
                #pragma unroll
                for (int e = 0; e < 4; ++e)
                    acc[rr][e] = fminf(acc[rr][e], d[rr] + rv[e]);
        }
        #pragma unroll
        for (int rr = 0; rr < 4; ++rr) {
            const int a = 4*a2 + rr;
            *reinterpret_cast<float4*>(
                &lds[obase + a*128 + ((ch ^ (a & 7)) << 2)]) =
                make_float4(acc[rr][0], acc[rr][1], acc[rr][2], acc[rr][3]);
        }
    }
}

// phase C: dd = min(dd, C_new[i][k] + R_new[k][j]) over 16 k
__device__ __forceinline__ void phaseC(float (&dd)[4][8], float* lds,
                                       const int rgrp, const int cgrp)
{
    #pragma unroll
    for (int kp = 0; kp < 8; ++kp) {
        const int k0 = 2*kp, k1 = 2*kp + 1;
        float4 cp0 = *reinterpret_cast<const float4*>(&lds[CP_N + k0*128 + ((rgrp      ^ (k0&7)) << 2)]);
        float4 r0a = *reinterpret_cast<const float4*>(&lds[RP_N + k0*128 + ((cgrp      ^ (k0&7)) << 2)]);
        float4 r0b = *reinterpret_cast<const float4*>(&lds[RP_N + k0*128 + (((cgrp+16) ^ (k0&7)) << 2)]);
        float4 cp1 = *reinterpret_cast<const float4*>(&lds[CP_N + k1*128 + ((rgrp      ^ (k1&7)) << 2)]);
        float4 r1a = *reinterpret_cast<const float4*>(&lds[RP_N + k1*128 + ((cgrp      ^ (k1&7)) << 2)]);
        float4 r1b = *reinterpret_cast<const float4*>(&lds[RP_N + k1*128 + (((cgrp+16) ^ (k1&7)) << 2)]);
        const float c0[4]  = {cp0.x, cp0.y, cp0.z, cp0.w};
        const float c1[4]  = {cp1.x, cp1.y, cp1.z, cp1.w};
        const float ra0[4] = {r0a.x, r0a.y, r0a.z, r0a.w};
        const float rb0[4] = {r0b.x, r0b.y, r0b.z, r0b.w};
        const float ra1[4] = {r1a.x, r1a.y, r1a.z, r1a.w};
        const float rb1[4] = {r1b.x, r1b.y, r1b.z, r1b.w};
        #pragma unroll
        for (int rr = 0; rr < 4; ++rr) {
            #pragma unroll
            for (int e = 0; e < 4; ++e) {
                dd[rr][e]   = fminf(fminf(dd[rr][e],   c0[rr] + ra0[e]), c1[rr] + ra1[e]);
                dd[rr][4+e] = fminf(fminf(dd[rr][4+e], c0[rr] + rb0[e]), c1[rr] + rb1[e]);
            }
        }
    }
}

__global__ __launch_bounds__(NT)
void spb_fw_kernel(const int* __restrict__ edge_index,
                   const float* __restrict__ edge_weight,
                   const int num_edges, const int epg,
                   float* __restrict__ out)
{
    __shared__ float lds[NCELL];
    const float INF = __builtin_huge_valf();
    const int t    = threadIdx.x;
    const int g    = blockIdx.x;
    const int cgrp = t & 15;
    const int rgrp = t >> 4;

    // ---- init matrix (swizzled: elem(i,col) at i*128 + (col ^ ((i&7)<<2))) ----
    #pragma unroll
    for (int c = 0; c < 8; ++c) {
        const int m   = t + (c << 9);
        const int i   = m >> 5;
        const int scm = m & 31;
        const int c0  = (scm ^ (i & 7)) << 2;
        float4 v;
        v.x = (c0 + 0 == i) ? 0.0f : INF;
        v.y = (c0 + 1 == i) ? 0.0f : INF;
        v.z = (c0 + 2 == i) ? 0.0f : INF;
        v.w = (c0 + 3 == i) ? 0.0f : INF;
        *reinterpret_cast<float4*>(&lds[m << 2]) = v;
    }
    __syncthreads();

    // ---- scatter edges ----
    const int ebase = g * epg;
    for (int e = t; e < epg; e += NT) {
        const int idx = ebase + e;
        const int src = edge_index[idx];
        const int dst = edge_index[num_edges + idx];
        const float w = edge_weight[idx];
        const int u = src - g * NN;
        const int v = dst - g * NN;
        if (u != v && (unsigned)u < (unsigned)NN && (unsigned)v < (unsigned)NN) {
            const int a = (u << 7) + (v ^ ((u & 7) << 2));
            atomicMin(reinterpret_cast<int*>(&lds[a]), __float_as_int(w));
        }
    }
    __syncthreads();

    // ---- load matrix into registers: dd[rr][c*4+e] = d[4rgrp+rr][4cgrp+64c+e] ----
    float dd[4][8];
    #pragma unroll
    for (int rr = 0; rr < 4; ++rr) {
        const int i = (rgrp << 2) + rr;
        const int s = i & 7;
        #pragma unroll
        for (int c = 0; c < 2; ++c) {
            float4 v = *reinterpret_cast<const float4*>(
                &lds[(i << 7) + (((cgrp + 16*c) ^ s) << 2)]);
            dd[rr][c*4+0]=v.x; dd[rr][c*4+1]=v.y; dd[rr][c*4+2]=v.z; dd[rr][c*4+3]=v.w;
        }
    }
    __syncthreads();   // matrix region dead; panels may be written

    // ---- pipelined blocked FW: prep(0); {B; bar; C+prep(next); bar} x8 ----
    prep_next<0>(dd, lds, 0, t, rgrp, cgrp);
    __syncthreads();
    #pragma unroll
    for (int kb = 0; kb < 8; ++kb) {
        phaseB(lds, t);
        __syncthreads();
        phaseC(dd, lds, rgrp, cgrp);
        if (kb < 7) {
            const int kbn = kb + 1;
            if (kbn < 4) prep_next<0>(dd, lds, kbn, t, rgrp, cgrp);
            else         prep_next<4>(dd, lds, kbn, t, rgrp, cgrp);
        }
        __syncthreads();
    }

    // ---- reductions ----
    float mF = 0.0f, mA = 0.0f;
    #pragma unroll
    for (int rr = 0; rr < 4; ++rr)
        #pragma unroll
        for (int j = 0; j < 8; ++j) {
            const float v = dd[rr][j];
            mA = fmaxf(mA, v);
            mF = fmaxf(mF, v < INF ? v : 0.0f);
        }
    #pragma unroll
    for (int o = 32; o > 0; o >>= 1) {
        mF = fmaxf(mF, __shfl_xor(mF, o));
        mA = fmaxf(mA, __shfl_xor(mA, o));
    }
    if ((t & 63) == 0) {
        lds[RED + ((t >> 6) << 1)]     = mF;
        lds[RED + ((t >> 6) << 1) + 1] = mA;
    }
    __syncthreads();
    mF = lds[RED]; mA = lds[RED + 1];
    #pragma unroll
    for (int wv = 1; wv < 8; ++wv) {
        mF = fmaxf(mF, lds[RED + wv*2]);
        mA = fmaxf(mA, lds[RED + wv*2 + 1]);
    }
    const float twoF  = 2.0f * mF;
    const float maxv  = fmaxf((mA == INF) ? twoF : mF, 1e-8f);
    const float nscal = -SCALE_F / maxv;

    // ---- normalize in registers, store 8 heads (coalesced, nontemporal) ----
    float* const outg = out + (size_t)g * (NHEADS * NCELL);
    #pragma unroll
    for (int rr = 0; rr < 4; ++rr) {
        const int i = (rgrp << 2) + rr;
        #pragma unroll
        for (int c = 0; c < 2; ++c) {
            nfloat4 v;
            v.x = ((dd[rr][c*4+0] == INF) ? twoF : dd[rr][c*4+0]) * nscal;
            v.y = ((dd[rr][c*4+1] == INF) ? twoF : dd[rr][c*4+1]) * nscal;
            v.z = ((dd[rr][c*4+2] == INF) ? twoF : dd[rr][c*4+2]) * nscal;
            v.w = ((dd[rr][c*4+3] == INF) ? twoF : dd[rr][c*4+3]) * nscal;
            const int o = (i << 7) + (cgrp << 2) + (c << 6);
            #pragma unroll
            for (int h = 0; h < NHEADS; ++h) {
                __builtin_nontemporal_store(
                    v, reinterpret_cast<nfloat4*>(&outg[h * NCELL + o]));
            }
        }
    }
}

extern "C" void kernel_launch(void* const* d_in, const int* in_sizes, int n_in,
                              void* d_out, int out_size, void* d_ws, size_t ws_size,
                              hipStream_t stream)
{
    const int*   edge_index  = (const int*)d_in[0];
    const float* edge_w      = (const float*)d_in[1];
    const int E    = in_sizes[1];
    const int Ntot = in_sizes[2];
    const int G    = Ntot / NN;
    const int epg  = E / G;
    float* out = (float*)d_out;
    spb_fw_kernel<<<G, NT, 0, stream>>>(edge_index, edge_w, E, epg, out);
}

// Round 7
// 67.412 us; speedup vs baseline: 1.1124x; 1.1124x over previous
//
#include <hip/hip_runtime.h>

#define NHEADS 8
#define NN     128
#define NCELL  (NN * NN)       // 16384 floats = 64 KiB
#define NT     512             // 8 waves
#define SCALE_F 10.0f

typedef float nfloat4 __attribute__((ext_vector_type(4)));

// Blocked Floyd-Warshall, B=16, one block (512 thr) per graph.
// Thread t: rgrp=t>>4 (rows 4rgrp..+4), cgrp=t&15 (cols 4cgrp+64c+e, c=0..1).
// dd[4][8] register-resident.
// Per step kb (2 barriers):
//   closure (wave kb, readlane-FW on diag tile -> D*) ; bar
//   B' : R_new = D* (x) R_old  (256 thr, only panel needed)   ; bar
//   C  : dd = min(dd, C_old[i][m] + R_new[m][j])   (identity: == C_new (x) R_new)
//   extract(kb+1): wave kb+1 -> RP_O + DP ; col owners -> CP[parity]
// Panels UNSWIZZLED (access patterns are row-covering / broadcast = conflict-free);
// matrix staging region keeps its XOR swizzle for the edge scatter.
//
// LDS float offsets:
#define RP_O 0        // [16][128] R_old
#define RP_N 2048     // [16][128] R_new
#define CP_As 4096    // [16][132] C_oldT, parity 0 (132 pad: conflict-free extract)
#define CP_Bs 6208    // [16][132] parity 1
#define DP   8320     // [16][20]  diag tile / D*
#define RED  8640

template<int CBN>   // CBN = 4*(kbn>>2): dd column-half holding block kbn's cols
__device__ __forceinline__ void extract_panels(const float (&dd)[4][8], float* lds,
                                               const int kbn, const int t,
                                               const int rgrp, const int cgrp,
                                               const int cpbase)
{
    // row panel (wave kbn)
    if ((rgrp >> 2) == kbn) {
        const int q = rgrp & 3;
        #pragma unroll
        for (int rr = 0; rr < 4; ++rr) {
            const int iloc = 4 * q + rr;
            #pragma unroll
            for (int c = 0; c < 2; ++c) {
                *reinterpret_cast<float4*>(
                    &lds[RP_O + iloc * 128 + (cgrp << 2) + (c << 6)]) =
                    make_float4(dd[rr][c*4+0], dd[rr][c*4+1],
                                dd[rr][c*4+2], dd[rr][c*4+3]);
            }
        }
        // diag tile (16 threads of wave kbn)
        const int p = cgrp - 4 * (kbn & 3);
        if ((unsigned)p < 4u) {
            #pragma unroll
            for (int rr = 0; rr < 4; ++rr) {
                *reinterpret_cast<float4*>(&lds[DP + (4*q+rr) * 20 + (p << 2)]) =
                    make_float4(dd[rr][CBN+0], dd[rr][CBN+1],
                                dd[rr][CBN+2], dd[rr][CBN+3]);
            }
        }
    }
    // col panel (owners spread over all waves), transposed: CPT[m][i]
    {
        const int q2 = cgrp - 4 * (kbn & 3);
        if ((unsigned)q2 < 4u) {
            #pragma unroll
            for (int e = 0; e < 4; ++e) {
                const int m = 4 * q2 + e;
                *reinterpret_cast<float4*>(&lds[cpbase + m * 132 + (rgrp << 2)]) =
                    make_float4(dd[0][CBN+e], dd[1][CBN+e],
                                dd[2][CBN+e], dd[3][CBN+e]);
            }
        }
    }
}

// wave kb: FW-close the 16x16 diag tile via readlane, D* back into DP
__device__ __forceinline__ void closure(float* lds, const int t, const int kb)
{
    if ((t >> 6) == kb) {
        asm volatile("s_waitcnt lgkmcnt(0)" ::: "memory");
        const int l  = t & 63;
        const int lr = l & 15;                 // row (4x duplicated)
        float T[16];
        #pragma unroll
        for (int c4 = 0; c4 < 4; ++c4) {
            float4 v = *reinterpret_cast<const float4*>(&lds[DP + lr*20 + (c4<<2)]);
            T[c4*4+0]=v.x; T[c4*4+1]=v.y; T[c4*4+2]=v.z; T[c4*4+3]=v.w;
        }
        #pragma unroll
        for (int k = 0; k < 16; ++k) {
            float rk[16];
            #pragma unroll
            for (int j = 0; j < 16; ++j)
                rk[j] = __int_as_float(
                    __builtin_amdgcn_readlane(__float_as_int(T[j]), k));
            const float dik = T[k];
            #pragma unroll
            for (int j = 0; j < 16; ++j)
                T[j] = fminf(T[j], dik + rk[j]);
        }
        if (l < 16) {
            #pragma unroll
            for (int c4 = 0; c4 < 4; ++c4)
                *reinterpret_cast<float4*>(&lds[DP + l*20 + (c4<<2)]) =
                    make_float4(T[c4*4], T[c4*4+1], T[c4*4+2], T[c4*4+3]);
        }
    }
}

// B': R_new[r][j] = min_m D*[r][m] + R_old[m][j]; 256 threads, 2 rows each
__device__ __forceinline__ void bprime(float* lds, const int t)
{
    if (t < 256) {
        const float INF = __builtin_huge_valf();
        const int k2 = t >> 5;        // rows 2k2, 2k2+1
        const int ch = t & 31;
        float da[16], db[16];
        #pragma unroll
        for (int c4 = 0; c4 < 4; ++c4) {
            float4 va = *reinterpret_cast<const float4*>(&lds[DP + (2*k2  )*20 + (c4<<2)]);
            float4 vb = *reinterpret_cast<const float4*>(&lds[DP + (2*k2+1)*20 + (c4<<2)]);
            da[c4*4+0]=va.x; da[c4*4+1]=va.y; da[c4*4+2]=va.z; da[c4*4+3]=va.w;
            db[c4*4+0]=vb.x; db[c4*4+1]=vb.y; db[c4*4+2]=vb.z; db[c4*4+3]=vb.w;
        }
        float aA[4] = {INF, INF, INF, INF};
        float aB[4] = {INF, INF, INF, INF};
        #pragma unroll
        for (int mp = 0; mp < 8; ++mp) {
            const int m0 = 2*mp, m1 = 2*mp + 1;
            float4 r0 = *reinterpret_cast<const float4*>(&lds[RP_O + m0*128 + (ch<<2)]);
            float4 r1 = *reinterpret_cast<const float4*>(&lds[RP_O + m1*128 + (ch<<2)]);
            const float rv0[4] = {r0.x, r0.y, r0.z, r0.w};
            const float rv1[4] = {r1.x, r1.y, r1.z, r1.w};
            #pragma unroll
            for (int e = 0; e < 4; ++e) {
                aA[e] = fminf(fminf(aA[e], da[m0] + rv0[e]), da[m1] + rv1[e]);
                aB[e] = fminf(fminf(aB[e], db[m0] + rv0[e]), db[m1] + rv1[e]);
            }
        }
        *reinterpret_cast<float4*>(&lds[RP_N + (2*k2  )*128 + (ch<<2)]) =
            make_float4(aA[0], aA[1], aA[2], aA[3]);
        *reinterpret_cast<float4*>(&lds[RP_N + (2*k2+1)*128 + (ch<<2)]) =
            make_float4(aB[0], aB[1], aB[2], aB[3]);
    }
}

// C: dd = min(dd, C_old[i][m] + R_new[m][j]) over 16 m
__device__ __forceinline__ void cphase(float (&dd)[4][8], float* lds,
                                       const int rgrp, const int cgrp,
                                       const int cpbase)
{
    #pragma unroll
    for (int mp = 0; mp < 8; ++mp) {
        const int m0 = 2*mp, m1 = 2*mp + 1;
        float4 cp0 = *reinterpret_cast<const float4*>(&lds[cpbase + m0*132 + (rgrp<<2)]);
        float4 cp1 = *reinterpret_cast<const float4*>(&lds[cpbase + m1*132 + (rgrp<<2)]);
        float4 r0a = *reinterpret_cast<const float4*>(&lds[RP_N + m0*128 + (cgrp<<2)]);
        float4 r0b = *reinterpret_cast<const float4*>(&lds[RP_N + m0*128 + (cgrp<<2) + 64]);
        float4 r1a = *reinterpret_cast<const float4*>(&lds[RP_N + m1*128 + (cgrp<<2)]);
        float4 r1b = *reinterpret_cast<const float4*>(&lds[RP_N + m1*128 + (cgrp<<2) + 64]);
        const float c0[4]  = {cp0.x, cp0.y, cp0.z, cp0.w};
        const float c1[4]  = {cp1.x, cp1.y, cp1.z, cp1.w};
        const float ra0[4] = {r0a.x, r0a.y, r0a.z, r0a.w};
        const float rb0[4] = {r0b.x, r0b.y, r0b.z, r0b.w};
        const float ra1[4] = {r1a.x, r1a.y, r1a.z, r1a.w};
        const float rb1[4] = {r1b.x, r1b.y, r1b.z, r1b.w};
        #pragma unroll
        for (int rr = 0; rr < 4; ++rr) {
            #pragma unroll
            for (int e = 0; e < 4; ++e) {
                dd[rr][e]   = fminf(fminf(dd[rr][e],   c0[rr] + ra0[e]), c1[rr] + ra1[e]);
                dd[rr][4+e] = fminf(fminf(dd[rr][4+e], c0[rr] + rb0[e]), c1[rr] + rb1[e]);
            }
        }
    }
}

__global__ __launch_bounds__(NT)
void spb_fw_kernel(const int* __restrict__ edge_index,
                   const float* __restrict__ edge_weight,
                   const int num_edges, const int epg,
                   float* __restrict__ out)
{
    __shared__ float lds[NCELL];
    const float INF = __builtin_huge_valf();
    const int t    = threadIdx.x;
    const int g    = blockIdx.x;
    const int cgrp = t & 15;
    const int rgrp = t >> 4;

    // ---- init matrix (swizzled: elem(i,col) at i*128 + (col ^ ((i&7)<<2))) ----
    #pragma unroll
    for (int c = 0; c < 8; ++c) {
        const int m   = t + (c << 9);
        const int i   = m >> 5;
        const int scm = m & 31;
        const int c0  = (scm ^ (i & 7)) << 2;
        float4 v;
        v.x = (c0 + 0 == i) ? 0.0f : INF;
        v.y = (c0 + 1 == i) ? 0.0f : INF;
        v.z = (c0 + 2 == i) ? 0.0f : INF;
        v.w = (c0 + 3 == i) ? 0.0f : INF;
        *reinterpret_cast<float4*>(&lds[m << 2]) = v;
    }
    __syncthreads();

    // ---- scatter edges (atomicMin; positive floats: int order == float order) ----
    const int ebase = g * epg;
    for (int e = t; e < epg; e += NT) {
        const int idx = ebase + e;
        const int src = edge_index[idx];
        const int dst = edge_index[num_edges + idx];
        const float w = edge_weight[idx];
        const int u = src - g * NN;
        const int v = dst - g * NN;
        if (u != v && (unsigned)u < (unsigned)NN && (unsigned)v < (unsigned)NN) {
            const int a = (u << 7) + (v ^ ((u & 7) << 2));
            atomicMin(reinterpret_cast<int*>(&lds[a]), __float_as_int(w));
        }
    }
    __syncthreads();

    // ---- load matrix into registers: dd[rr][c*4+e] = d[4rgrp+rr][4cgrp+64c+e] ----
    float dd[4][8];
    #pragma unroll
    for (int rr = 0; rr < 4; ++rr) {
        const int i = (rgrp << 2) + rr;
        const int s = i & 7;
        #pragma unroll
        for (int c = 0; c < 2; ++c) {
            float4 v = *reinterpret_cast<const float4*>(
                &lds[(i << 7) + (((cgrp + 16*c) ^ s) << 2)]);
            dd[rr][c*4+0]=v.x; dd[rr][c*4+1]=v.y; dd[rr][c*4+2]=v.z; dd[rr][c*4+3]=v.w;
        }
    }
    __syncthreads();   // matrix region dead; panels may be written

    // ---- blocked FW: 8 steps, 2 barriers each ----
    extract_panels<0>(dd, lds, 0, t, rgrp, cgrp, CP_As);
    #pragma unroll
    for (int kb = 0; kb < 8; ++kb) {
        closure(lds, t, kb);
        __syncthreads();
        bprime(lds, t);
        __syncthreads();
        cphase(dd, lds, rgrp, cgrp, (kb & 1) ? CP_Bs : CP_As);
        if (kb < 7) {
            const int kbn = kb + 1;
            const int cpb = (kbn & 1) ? CP_Bs : CP_As;
            if (kbn < 4) extract_panels<0>(dd, lds, kbn, t, rgrp, cgrp, cpb);
            else         extract_panels<4>(dd, lds, kbn, t, rgrp, cgrp, cpb);
        }
    }
    __syncthreads();

    // ---- reductions (max finite, global max) ----
    float mF = 0.0f, mA = 0.0f;
    #pragma unroll
    for (int rr = 0; rr < 4; ++rr)
        #pragma unroll
        for (int j = 0; j < 8; ++j) {
            const float v = dd[rr][j];
            mA = fmaxf(mA, v);
            mF = fmaxf(mF, v < INF ? v : 0.0f);
        }
    #pragma unroll
    for (int o = 32; o > 0; o >>= 1) {
        mF = fmaxf(mF, __shfl_xor(mF, o));
        mA = fmaxf(mA, __shfl_xor(mA, o));
    }
    if ((t & 63) == 0) {
        lds[RED + ((t >> 6) << 1)]     = mF;
        lds[RED + ((t >> 6) << 1) + 1] = mA;
    }
    __syncthreads();
    mF = lds[RED]; mA = lds[RED + 1];
    #pragma unroll
    for (int wv = 1; wv < 8; ++wv) {
        mF = fmaxf(mF, lds[RED + wv*2]);
        mA = fmaxf(mA, lds[RED + wv*2 + 1]);
    }
    const float twoF  = 2.0f * mF;
    const float maxv  = fmaxf((mA == INF) ? twoF : mF, 1e-8f);
    const float nscal = -SCALE_F / maxv;

    // ---- normalize in registers, store 8 heads (coalesced, nontemporal) ----
    float* const outg = out + (size_t)g * (NHEADS * NCELL);
    #pragma unroll
    for (int rr = 0; rr < 4; ++rr) {
        const int i = (rgrp << 2) + rr;
        #pragma unroll
        for (int c = 0; c < 2; ++c) {
            nfloat4 v;
            v.x = ((dd[rr][c*4+0] == INF) ? twoF : dd[rr][c*4+0]) * nscal;
            v.y = ((dd[rr][c*4+1] == INF) ? twoF : dd[rr][c*4+1]) * nscal;
            v.z = ((dd[rr][c*4+2] == INF) ? twoF : dd[rr][c*4+2]) * nscal;
            v.w = ((dd[rr][c*4+3] == INF) ? twoF : dd[rr][c*4+3]) * nscal;
            const int o = (i << 7) + (cgrp << 2) + (c << 6);
            #pragma unroll
            for (int h = 0; h < NHEADS; ++h) {
                __builtin_nontemporal_store(
                    v, reinterpret_cast<nfloat4*>(&outg[h * NCELL + o]));
            }
        }
    }
}

extern "C" void kernel_launch(void* const* d_in, const int* in_sizes, int n_in,
                              void* d_out, int out_size, void* d_ws, size_t ws_size,
                              hipStream_t stream)
{
    const int*   edge_index  = (const int*)d_in[0];
    const float* edge_w      = (const float*)d_in[1];
    const int E    = in_sizes[1];
    const int Ntot = in_sizes[2];
    const int G    = Ntot / NN;
    const int epg  = E / G;
    float* out = (float*)d_out;
    spb_fw_kernel<<<G, NT, 0, stream>>>(edge_index, edge_w, E, epg, out);
}

// Round 8
// 62.942 us; speedup vs baseline: 1.1915x; 1.0710x over previous
//
#include <hip/hip_runtime.h>

#define NHEADS 8
#define NN     128
#define NCELL  (NN * NN)       // 16384 floats = 64 KiB
#define NT     512             // 8 waves
#define SCALE_F 10.0f

typedef float nfloat4 __attribute__((ext_vector_type(4)));

// Blocked Floyd-Warshall, B=16, one block (512 thr) per graph.
// Thread t: rgrp=t>>4 (rows 4rgrp..+4), cgrp=t&15 (cols 4cgrp+64c+e, c=0..1).
// dd[4][8] register-resident.
// Per step kb (2 barriers):
//   closure (wave kb, WAVE-PARALLEL shfl-FW on diag tile -> D*) ; bar
//   B' : R_new = D* (x) R_old  (256 thr)                         ; bar
//   C  : dd = min(dd, C_old[i][m] + R_new[m][j])  (== C_new (x) R_new identity)
//   extract(kb+1): wave kb+1 -> RP_O + DP ; col owners -> CP[parity]
// kb loop is ROLLED (#pragma unroll 1): body ~1.8k instrs stays L1I-resident
// (fully unrolled was ~115KB streaming through a 32KB L1I with zero reuse).
//
// LDS float offsets:
#define RP_O 0        // [16][128] R_old
#define RP_N 2048     // [16][128] R_new
#define CP_As 4096    // [16][132] C_oldT, parity 0
#define CP_Bs 6208    // [16][132] parity 1
#define DP   8320     // [16][20]  diag tile / D*
#define RED  8640

template<int CBN>   // CBN = 4*(kbn>>2): dd column-half holding block kbn's cols
__device__ __forceinline__ void extract_panels(const float (&dd)[4][8], float* lds,
                                               const int kbn, const int t,
                                               const int rgrp, const int cgrp,
                                               const int cpbase)
{
    // row panel + diag tile (wave kbn)
    if ((rgrp >> 2) == kbn) {
        const int q = rgrp & 3;
        #pragma unroll
        for (int rr = 0; rr < 4; ++rr) {
            const int iloc = 4 * q + rr;
            #pragma unroll
            for (int c = 0; c < 2; ++c) {
                *reinterpret_cast<float4*>(
                    &lds[RP_O + iloc * 128 + (cgrp << 2) + (c << 6)]) =
                    make_float4(dd[rr][c*4+0], dd[rr][c*4+1],
                                dd[rr][c*4+2], dd[rr][c*4+3]);
            }
        }
        const int p = cgrp - 4 * (kbn & 3);
        if ((unsigned)p < 4u) {
            #pragma unroll
            for (int rr = 0; rr < 4; ++rr) {
                *reinterpret_cast<float4*>(&lds[DP + (4*q+rr) * 20 + (p << 2)]) =
                    make_float4(dd[rr][CBN+0], dd[rr][CBN+1],
                                dd[rr][CBN+2], dd[rr][CBN+3]);
            }
        }
    }
    // col panel (owners spread over all waves), transposed: CPT[m][i]
    {
        const int q2 = cgrp - 4 * (kbn & 3);
        if ((unsigned)q2 < 4u) {
            #pragma unroll
            for (int e = 0; e < 4; ++e) {
                const int m = 4 * q2 + e;
                *reinterpret_cast<float4*>(&lds[cpbase + m * 132 + (rgrp << 2)]) =
                    make_float4(dd[0][CBN+e], dd[1][CBN+e],
                                dd[2][CBN+e], dd[3][CBN+e]);
            }
        }
    }
}

// wave kb: FW-close the 16x16 diag tile, wave-parallel.
// lane l owns row i=l&15, cols 4*(l>>4)..+3 (4 cells). Per k: 5 shfls + 8 VALU.
// In-place exactness: row k / col k are fixed points of step k (diag == 0).
__device__ __forceinline__ void closure(float* lds, const int t, const int kb)
{
    if ((t >> 6) == kb) {
        asm volatile("s_waitcnt lgkmcnt(0)" ::: "memory");
        const int l  = t & 63;
        const int i  = l & 15;
        const int jq = l >> 4;
        float4 v = *reinterpret_cast<const float4*>(&lds[DP + i*20 + (jq << 2)]);
        float T0 = v.x, T1 = v.y, T2 = v.z, T3 = v.w;
        #pragma unroll
        for (int k = 0; k < 16; ++k) {
            // d[i][k] from lane ((k>>2)<<4) | i, elem k&3
            const int ksrc = ((k >> 2) << 4) | i;
            float dik;
            switch (k & 3) {
                case 0: dik = __shfl(T0, ksrc); break;
                case 1: dik = __shfl(T1, ksrc); break;
                case 2: dik = __shfl(T2, ksrc); break;
                default: dik = __shfl(T3, ksrc); break;
            }
            // d[k][4jq..+3] from lane (jq<<4) | k
            const int rsrc = (jq << 4) | k;
            const float r0 = __shfl(T0, rsrc);
            const float r1 = __shfl(T1, rsrc);
            const float r2 = __shfl(T2, rsrc);
            const float r3 = __shfl(T3, rsrc);
            T0 = fminf(T0, dik + r0);
            T1 = fminf(T1, dik + r1);
            T2 = fminf(T2, dik + r2);
            T3 = fminf(T3, dik + r3);
        }
        *reinterpret_cast<float4*>(&lds[DP + i*20 + (jq << 2)]) =
            make_float4(T0, T1, T2, T3);
    }
}

// B': R_new[r][j] = min_m D*[r][m] + R_old[m][j]; 256 threads, 2 rows each
__device__ __forceinline__ void bprime(float* lds, const int t)
{
    if (t < 256) {
        const float INF = __builtin_huge_valf();
        const int k2 = t >> 5;        // rows 2k2, 2k2+1
        const int ch = t & 31;
        float da[16], db[16];
        #pragma unroll
        for (int c4 = 0; c4 < 4; ++c4) {
            float4 va = *reinterpret_cast<const float4*>(&lds[DP + (2*k2  )*20 + (c4<<2)]);
            float4 vb = *reinterpret_cast<const float4*>(&lds[DP + (2*k2+1)*20 + (c4<<2)]);
            da[c4*4+0]=va.x; da[c4*4+1]=va.y; da[c4*4+2]=va.z; da[c4*4+3]=va.w;
            db[c4*4+0]=vb.x; db[c4*4+1]=vb.y; db[c4*4+2]=vb.z; db[c4*4+3]=vb.w;
        }
        float aA[4] = {INF, INF, INF, INF};
        float aB[4] = {INF, INF, INF, INF};
        #pragma unroll
        for (int mp = 0; mp < 8; ++mp) {
            const int m0 = 2*mp, m1 = 2*mp + 1;
            float4 r0 = *reinterpret_cast<const float4*>(&lds[RP_O + m0*128 + (ch<<2)]);
            float4 r1 = *reinterpret_cast<const float4*>(&lds[RP_O + m1*128 + (ch<<2)]);
            const float rv0[4] = {r0.x, r0.y, r0.z, r0.w};
            const float rv1[4] = {r1.x, r1.y, r1.z, r1.w};
            #pragma unroll
            for (int e = 0; e < 4; ++e) {
                aA[e] = fminf(fminf(aA[e], da[m0] + rv0[e]), da[m1] + rv1[e]);
                aB[e] = fminf(fminf(aB[e], db[m0] + rv0[e]), db[m1] + rv1[e]);
            }
        }
        *reinterpret_cast<float4*>(&lds[RP_N + (2*k2  )*128 + (ch<<2)]) =
            make_float4(aA[0], aA[1], aA[2], aA[3]);
        *reinterpret_cast<float4*>(&lds[RP_N + (2*k2+1)*128 + (ch<<2)]) =
            make_float4(aB[0], aB[1], aB[2], aB[3]);
    }
}

// C: dd = min(dd, C_old[i][m] + R_new[m][j]) over 16 m
__device__ __forceinline__ void cphase(float (&dd)[4][8], float* lds,
                                       const int rgrp, const int cgrp,
                                       const int cpbase)
{
    #pragma unroll
    for (int mp = 0; mp < 8; ++mp) {
        const int m0 = 2*mp, m1 = 2*mp + 1;
        float4 cp0 = *reinterpret_cast<const float4*>(&lds[cpbase + m0*132 + (rgrp<<2)]);
        float4 cp1 = *reinterpret_cast<const float4*>(&lds[cpbase + m1*132 + (rgrp<<2)]);
        float4 r0a = *reinterpret_cast<const float4*>(&lds[RP_N + m0*128 + (cgrp<<2)]);
        float4 r0b = *reinterpret_cast<const float4*>(&lds[RP_N + m0*128 + (cgrp<<2) + 64]);
        float4 r1a = *reinterpret_cast<const float4*>(&lds[RP_N + m1*128 + (cgrp<<2)]);
        float4 r1b = *reinterpret_cast<const float4*>(&lds[RP_N + m1*128 + (cgrp<<2) + 64]);
        const float c0[4]  = {cp0.x, cp0.y, cp0.z, cp0.w};
        const float c1[4]  = {cp1.x, cp1.y, cp1.z, cp1.w};
        const float ra0[4] = {r0a.x, r0a.y, r0a.z, r0a.w};
        const float rb0[4] = {r0b.x, r0b.y, r0b.z, r0b.w};
        const float ra1[4] = {r1a.x, r1a.y, r1a.z, r1a.w};
        const float rb1[4] = {r1b.x, r1b.y, r1b.z, r1b.w};
        #pragma unroll
        for (int rr = 0; rr < 4; ++rr) {
            #pragma unroll
            for (int e = 0; e < 4; ++e) {
                dd[rr][e]   = fminf(fminf(dd[rr][e],   c0[rr] + ra0[e]), c1[rr] + ra1[e]);
                dd[rr][4+e] = fminf(fminf(dd[rr][4+e], c0[rr] + rb0[e]), c1[rr] + rb1[e]);
            }
        }
    }
}

__global__ __launch_bounds__(NT)
void spb_fw_kernel(const int* __restrict__ edge_index,
                   const float* __restrict__ edge_weight,
                   const int num_edges, const int epg,
                   float* __restrict__ out)
{
    __shared__ float lds[NCELL];
    const float INF = __builtin_huge_valf();
    const int t    = threadIdx.x;
    const int g    = blockIdx.x;
    const int cgrp = t & 15;
    const int rgrp = t >> 4;

    // ---- init matrix (swizzled: elem(i,col) at i*128 + (col ^ ((i&7)<<2))) ----
    #pragma unroll
    for (int c = 0; c < 8; ++c) {
        const int m   = t + (c << 9);
        const int i   = m >> 5;
        const int scm = m & 31;
        const int c0  = (scm ^ (i & 7)) << 2;
        float4 v;
        v.x = (c0 + 0 == i) ? 0.0f : INF;
        v.y = (c0 + 1 == i) ? 0.0f : INF;
        v.z = (c0 + 2 == i) ? 0.0f : INF;
        v.w = (c0 + 3 == i) ? 0.0f : INF;
        *reinterpret_cast<float4*>(&lds[m << 2]) = v;
    }
    __syncthreads();

    // ---- scatter edges (atomicMin; positive floats: int order == float order) ----
    const int ebase = g * epg;
    for (int e = t; e < epg; e += NT) {
        const int idx = ebase + e;
        const int src = edge_index[idx];
        const int dst = edge_index[num_edges + idx];
        const float w = edge_weight[idx];
        const int u = src - g * NN;
        const int v = dst - g * NN;
        if (u != v && (unsigned)u < (unsigned)NN && (unsigned)v < (unsigned)NN) {
            const int a = (u << 7) + (v ^ ((u & 7) << 2));
            atomicMin(reinterpret_cast<int*>(&lds[a]), __float_as_int(w));
        }
    }
    __syncthreads();

    // ---- load matrix into registers: dd[rr][c*4+e] = d[4rgrp+rr][4cgrp+64c+e] ----
    float dd[4][8];
    #pragma unroll
    for (int rr = 0; rr < 4; ++rr) {
        const int i = (rgrp << 2) + rr;
        const int s = i & 7;
        #pragma unroll
        for (int c = 0; c < 2; ++c) {
            float4 v = *reinterpret_cast<const float4*>(
                &lds[(i << 7) + (((cgrp + 16*c) ^ s) << 2)]);
            dd[rr][c*4+0]=v.x; dd[rr][c*4+1]=v.y; dd[rr][c*4+2]=v.z; dd[rr][c*4+3]=v.w;
        }
    }
    __syncthreads();   // matrix region dead; panels may be written

    // ---- blocked FW: 8 steps, 2 barriers each (ROLLED loop) ----
    extract_panels<0>(dd, lds, 0, t, rgrp, cgrp, CP_As);
    #pragma unroll 1
    for (int kb = 0; kb < 8; ++kb) {
        closure(lds, t, kb);
        __syncthreads();
        bprime(lds, t);
        __syncthreads();
        cphase(dd, lds, rgrp, cgrp, (kb & 1) ? CP_Bs : CP_As);
        if (kb < 7) {
            const int kbn = kb + 1;
            const int cpb = (kbn & 1) ? CP_Bs : CP_As;
            if (kbn < 4) extract_panels<0>(dd, lds, kbn, t, rgrp, cgrp, cpb);
            else         extract_panels<4>(dd, lds, kbn, t, rgrp, cgrp, cpb);
        }
    }
    __syncthreads();

    // ---- reductions (max finite, global max) ----
    float mF = 0.0f, mA = 0.0f;
    #pragma unroll
    for (int rr = 0; rr < 4; ++rr)
        #pragma unroll
        for (int j = 0; j < 8; ++j) {
            const float v = dd[rr][j];
            mA = fmaxf(mA, v);
            mF = fmaxf(mF, v < INF ? v : 0.0f);
        }
    #pragma unroll
    for (int o = 32; o > 0; o >>= 1) {
        mF = fmaxf(mF, __shfl_xor(mF, o));
        mA = fmaxf(mA, __shfl_xor(mA, o));
    }
    if ((t & 63) == 0) {
        lds[RED + ((t >> 6) << 1)]     = mF;
        lds[RED + ((t >> 6) << 1) + 1] = mA;
    }
    __syncthreads();
    mF = lds[RED]; mA = lds[RED + 1];
    #pragma unroll
    for (int wv = 1; wv < 8; ++wv) {
        mF = fmaxf(mF, lds[RED + wv*2]);
        mA = fmaxf(mA, lds[RED + wv*2 + 1]);
    }
    const float twoF  = 2.0f * mF;
    const float maxv  = fmaxf((mA == INF) ? twoF : mF, 1e-8f);
    const float nscal = -SCALE_F / maxv;

    // ---- normalize in registers, store 8 heads (coalesced, nontemporal) ----
    float* const outg = out + (size_t)g * (NHEADS * NCELL);
    #pragma unroll
    for (int rr = 0; rr < 4; ++rr) {
        const int i = (rgrp << 2) + rr;
        #pragma unroll
        for (int c = 0; c < 2; ++c) {
            nfloat4 v;
            v.x = ((dd[rr][c*4+0] == INF) ? twoF : dd[rr][c*4+0]) * nscal;
            v.y = ((dd[rr][c*4+1] == INF) ? twoF : dd[rr][c*4+1]) * nscal;
            v.z = ((dd[rr][c*4+2] == INF) ? twoF : dd[rr][c*4+2]) * nscal;
            v.w = ((dd[rr][c*4+3] == INF) ? twoF : dd[rr][c*4+3]) * nscal;
            const int o = (i << 7) + (cgrp << 2) + (c << 6);
            #pragma unroll
            for (int h = 0; h < NHEADS; ++h) {
                __builtin_nontemporal_store(
                    v, reinterpret_cast<nfloat4*>(&outg[h * NCELL + o]));
            }
        }
    }
}

extern "C" void kernel_launch(void* const* d_in, const int* in_sizes, int n_in,
                              void* d_out, int out_size, void* d_ws, size_t ws_size,
                              hipStream_t stream)
{
    const int*   edge_index  = (const int*)d_in[0];
    const float* edge_w      = (const float*)d_in[1];
    const int E    = in_sizes[1];
    const int Ntot = in_sizes[2];
    const int G    = Ntot / NN;
    const int epg  = E / G;
    float* out = (float*)d_out;
    spb_fw_kernel<<<G, NT, 0, stream>>>(edge_index, edge_w, E, epg, out);
}

// Round 9
// 61.647 us; speedup vs baseline: 1.2165x; 1.0210x over previous
//
#include <hip/hip_runtime.h>

#define NHEADS 8
#define NN     128
#define NCELL  (NN * NN)       // 16384 floats = 64 KiB
#define NT     512             // 8 waves
#define SCALE_F 10.0f

typedef float nfloat4 __attribute__((ext_vector_type(4)));

// Blocked Floyd-Warshall, B=16, one block (512 thr) per graph. 1 block/CU.
// Thread t: rgrp=t>>4 (rows 4rgrp..+4), cgrp=t&15 (cols 4cgrp+64c+e, c=0..1).
// dd[4][8] register-resident.
// Per step kb (2 barriers):
//   closure (wave kb, wave-parallel shfl-FW on diag tile -> D*) ; bar
//   B' : R_new = D* (x) R_old  (256 thr)                         ; bar
//   C  : dd = min(dd, C_old[i][m] + R_new[m][j])  (== C_new (x) R_new identity)
//   extract(kb+1): wave kb+1 -> RP_O + DP ; col owners -> CP[parity]
// kb loop ROLLED (L1I residency). __launch_bounds__(512,2): we run 2 waves/SIMD
// (grid == CU count), so let the allocator use ~256 VGPR to pipeline C's loads.
//
// LDS float offsets:
#define RP_O 0        // [16][128] R_old
#define RP_N 2048     // [16][128] R_new
#define CP_As 4096    // [16][132] C_oldT, parity 0
#define CP_Bs 6208    // [16][132] parity 1
#define DP   8320     // [16][20]  diag tile / D*
#define RED  8640

template<int CBN>   // CBN = 4*(kbn>>2): dd column-half holding block kbn's cols
__device__ __forceinline__ void extract_panels(const float (&dd)[4][8], float* lds,
                                               const int kbn, const int t,
                                               const int rgrp, const int cgrp,
                                               const int cpbase)
{
    // row panel + diag tile (wave kbn)
    if ((rgrp >> 2) == kbn) {
        const int q = rgrp & 3;
        #pragma unroll
        for (int rr = 0; rr < 4; ++rr) {
            const int iloc = 4 * q + rr;
            #pragma unroll
            for (int c = 0; c < 2; ++c) {
                *reinterpret_cast<float4*>(
                    &lds[RP_O + iloc * 128 + (cgrp << 2) + (c << 6)]) =
                    make_float4(dd[rr][c*4+0], dd[rr][c*4+1],
                                dd[rr][c*4+2], dd[rr][c*4+3]);
            }
        }
        const int p = cgrp - 4 * (kbn & 3);
        if ((unsigned)p < 4u) {
            #pragma unroll
            for (int rr = 0; rr < 4; ++rr) {
                *reinterpret_cast<float4*>(&lds[DP + (4*q+rr) * 20 + (p << 2)]) =
                    make_float4(dd[rr][CBN+0], dd[rr][CBN+1],
                                dd[rr][CBN+2], dd[rr][CBN+3]);
            }
        }
    }
    // col panel (owners spread over all waves), transposed: CPT[m][i]
    {
        const int q2 = cgrp - 4 * (kbn & 3);
        if ((unsigned)q2 < 4u) {
            #pragma unroll
            for (int e = 0; e < 4; ++e) {
                const int m = 4 * q2 + e;
                *reinterpret_cast<float4*>(&lds[cpbase + m * 132 + (rgrp << 2)]) =
                    make_float4(dd[0][CBN+e], dd[1][CBN+e],
                                dd[2][CBN+e], dd[3][CBN+e]);
            }
        }
    }
}

// wave kb: FW-close the 16x16 diag tile, wave-parallel.
// lane l owns row i=l&15, cols 4*(l>>4)..+3. In-place exact (diag==0).
__device__ __forceinline__ void closure(float* lds, const int t, const int kb)
{
    if ((t >> 6) == kb) {
        asm volatile("s_waitcnt lgkmcnt(0)" ::: "memory");
        const int l  = t & 63;
        const int i  = l & 15;
        const int jq = l >> 4;
        float4 v = *reinterpret_cast<const float4*>(&lds[DP + i*20 + (jq << 2)]);
        float T0 = v.x, T1 = v.y, T2 = v.z, T3 = v.w;
        #pragma unroll
        for (int k = 0; k < 16; ++k) {
            const int ksrc = ((k >> 2) << 4) | i;
            float dik;
            switch (k & 3) {
                case 0: dik = __shfl(T0, ksrc); break;
                case 1: dik = __shfl(T1, ksrc); break;
                case 2: dik = __shfl(T2, ksrc); break;
                default: dik = __shfl(T3, ksrc); break;
            }
            const int rsrc = (jq << 4) | k;
            const float r0 = __shfl(T0, rsrc);
            const float r1 = __shfl(T1, rsrc);
            const float r2 = __shfl(T2, rsrc);
            const float r3 = __shfl(T3, rsrc);
            T0 = fminf(T0, dik + r0);
            T1 = fminf(T1, dik + r1);
            T2 = fminf(T2, dik + r2);
            T3 = fminf(T3, dik + r3);
        }
        *reinterpret_cast<float4*>(&lds[DP + i*20 + (jq << 2)]) =
            make_float4(T0, T1, T2, T3);
    }
}

// B': R_new[r][j] = min_m D*[r][m] + R_old[m][j]; 256 threads, 2 rows each.
// All 16 R_old rows preloaded (32 regs) -> loads pipeline ahead of compute.
__device__ __forceinline__ void bprime(float* lds, const int t)
{
    if (t < 256) {
        const float INF = __builtin_huge_valf();
        const int k2 = t >> 5;
        const int ch = t & 31;
        float4 R[16];
        #pragma unroll
        for (int m = 0; m < 16; ++m)
            R[m] = *reinterpret_cast<const float4*>(&lds[RP_O + m*128 + (ch<<2)]);
        float da[16], db[16];
        #pragma unroll
        for (int c4 = 0; c4 < 4; ++c4) {
            float4 va = *reinterpret_cast<const float4*>(&lds[DP + (2*k2  )*20 + (c4<<2)]);
            float4 vb = *reinterpret_cast<const float4*>(&lds[DP + (2*k2+1)*20 + (c4<<2)]);
            da[c4*4+0]=va.x; da[c4*4+1]=va.y; da[c4*4+2]=va.z; da[c4*4+3]=va.w;
            db[c4*4+0]=vb.x; db[c4*4+1]=vb.y; db[c4*4+2]=vb.z; db[c4*4+3]=vb.w;
        }
        float aA[4] = {INF, INF, INF, INF};
        float aB[4] = {INF, INF, INF, INF};
        #pragma unroll
        for (int mp = 0; mp < 8; ++mp) {
            const int m0 = 2*mp, m1 = 2*mp + 1;
            const float rv0[4] = {R[m0].x, R[m0].y, R[m0].z, R[m0].w};
            const float rv1[4] = {R[m1].x, R[m1].y, R[m1].z, R[m1].w};
            #pragma unroll
            for (int e = 0; e < 4; ++e) {
                aA[e] = fminf(fminf(aA[e], da[m0] + rv0[e]), da[m1] + rv1[e]);
                aB[e] = fminf(fminf(aB[e], db[m0] + rv0[e]), db[m1] + rv1[e]);
            }
        }
        *reinterpret_cast<float4*>(&lds[RP_N + (2*k2  )*128 + (ch<<2)]) =
            make_float4(aA[0], aA[1], aA[2], aA[3]);
        *reinterpret_cast<float4*>(&lds[RP_N + (2*k2+1)*128 + (ch<<2)]) =
            make_float4(aB[0], aB[1], aB[2], aB[3]);
    }
}

// C: dd = min(dd, C_old[i][m] + R_new[m][j]) over 16 m.
// Chunked preload (4 m per chunk = 12 float4) so loads run ahead of compute.
__device__ __forceinline__ void cphase(float (&dd)[4][8], float* lds,
                                       const int rgrp, const int cgrp,
                                       const int cpbase)
{
    #pragma unroll
    for (int mq = 0; mq < 4; ++mq) {
        float4 cp[4], ra[4], rb[4];
        #pragma unroll
        for (int e = 0; e < 4; ++e) {
            const int m = 4*mq + e;
            cp[e] = *reinterpret_cast<const float4*>(&lds[cpbase + m*132 + (rgrp<<2)]);
            ra[e] = *reinterpret_cast<const float4*>(&lds[RP_N + m*128 + (cgrp<<2)]);
            rb[e] = *reinterpret_cast<const float4*>(&lds[RP_N + m*128 + (cgrp<<2) + 64]);
        }
        #pragma unroll
        for (int e2 = 0; e2 < 2; ++e2) {
            const float c0[4]  = {cp[2*e2].x, cp[2*e2].y, cp[2*e2].z, cp[2*e2].w};
            const float c1[4]  = {cp[2*e2+1].x, cp[2*e2+1].y, cp[2*e2+1].z, cp[2*e2+1].w};
            const float ra0[4] = {ra[2*e2].x, ra[2*e2].y, ra[2*e2].z, ra[2*e2].w};
            const float ra1[4] = {ra[2*e2+1].x, ra[2*e2+1].y, ra[2*e2+1].z, ra[2*e2+1].w};
            const float rb0[4] = {rb[2*e2].x, rb[2*e2].y, rb[2*e2].z, rb[2*e2].w};
            const float rb1[4] = {rb[2*e2+1].x, rb[2*e2+1].y, rb[2*e2+1].z, rb[2*e2+1].w};
            #pragma unroll
            for (int rr = 0; rr < 4; ++rr) {
                #pragma unroll
                for (int e = 0; e < 4; ++e) {
                    dd[rr][e]   = fminf(fminf(dd[rr][e],   c0[rr] + ra0[e]), c1[rr] + ra1[e]);
                    dd[rr][4+e] = fminf(fminf(dd[rr][4+e], c0[rr] + rb0[e]), c1[rr] + rb1[e]);
                }
            }
        }
    }
}

__global__ __launch_bounds__(NT, 2)   // 2 waves/SIMD: free the VGPR budget
void spb_fw_kernel(const int* __restrict__ edge_index,
                   const float* __restrict__ edge_weight,
                   const int num_edges, const int epg,
                   float* __restrict__ out)
{
    __shared__ float lds[NCELL];
    const float INF = __builtin_huge_valf();
    const int t    = threadIdx.x;
    const int g    = blockIdx.x;
    const int cgrp = t & 15;
    const int rgrp = t >> 4;

    // ---- prefetch this block's edges into registers (hide global latency) ----
    const int ebase = g * epg;
    int esrc[4], edst[4]; float ew[4];
    #pragma unroll
    for (int k = 0; k < 4; ++k) {
        int e = t + k * NT;
        e = (e < epg) ? e : (epg - 1);          // clamp; dup scatter is idempotent
        const int idx = ebase + e;
        esrc[k] = edge_index[idx];
        edst[k] = edge_index[num_edges + idx];
        ew[k]   = edge_weight[idx];
    }

    // ---- init matrix (swizzled: elem(i,col) at i*128 + (col ^ ((i&7)<<2))) ----
    #pragma unroll
    for (int c = 0; c < 8; ++c) {
        const int m   = t + (c << 9);
        const int i   = m >> 5;
        const int scm = m & 31;
        const int c0  = (scm ^ (i & 7)) << 2;
        float4 v;
        v.x = (c0 + 0 == i) ? 0.0f : INF;
        v.y = (c0 + 1 == i) ? 0.0f : INF;
        v.z = (c0 + 2 == i) ? 0.0f : INF;
        v.w = (c0 + 3 == i) ? 0.0f : INF;
        *reinterpret_cast<float4*>(&lds[m << 2]) = v;
    }
    __syncthreads();

    // ---- scatter edges from registers (atomicMin on int view) ----
    #pragma unroll
    for (int k = 0; k < 4; ++k) {
        const int u = esrc[k] - g * NN;
        const int v = edst[k] - g * NN;
        if (u != v && (unsigned)u < (unsigned)NN && (unsigned)v < (unsigned)NN) {
            const int a = (u << 7) + (v ^ ((u & 7) << 2));
            atomicMin(reinterpret_cast<int*>(&lds[a]), __float_as_int(ew[k]));
        }
    }
    __syncthreads();

    // ---- load matrix into registers: dd[rr][c*4+e] = d[4rgrp+rr][4cgrp+64c+e] ----
    float dd[4][8];
    #pragma unroll
    for (int rr = 0; rr < 4; ++rr) {
        const int i = (rgrp << 2) + rr;
        const int s = i & 7;
        #pragma unroll
        for (int c = 0; c < 2; ++c) {
            float4 v = *reinterpret_cast<const float4*>(
                &lds[(i << 7) + (((cgrp + 16*c) ^ s) << 2)]);
            dd[rr][c*4+0]=v.x; dd[rr][c*4+1]=v.y; dd[rr][c*4+2]=v.z; dd[rr][c*4+3]=v.w;
        }
    }
    __syncthreads();   // matrix region dead; panels may be written

    // ---- blocked FW: 8 steps, 2 barriers each (ROLLED loop) ----
    extract_panels<0>(dd, lds, 0, t, rgrp, cgrp, CP_As);
    #pragma unroll 1
    for (int kb = 0; kb < 8; ++kb) {
        closure(lds, t, kb);
        __syncthreads();
        bprime(lds, t);
        __syncthreads();
        cphase(dd, lds, rgrp, cgrp, (kb & 1) ? CP_Bs : CP_As);
        if (kb < 7) {
            const int kbn = kb + 1;
            const int cpb = (kbn & 1) ? CP_Bs : CP_As;
            if (kbn < 4) extract_panels<0>(dd, lds, kbn, t, rgrp, cgrp, cpb);
            else         extract_panels<4>(dd, lds, kbn, t, rgrp, cgrp, cpb);
        }
    }
    __syncthreads();

    // ---- reductions (max finite, global max) ----
    float mF = 0.0f, mA = 0.0f;
    #pragma unroll
    for (int rr = 0; rr < 4; ++rr)
        #pragma unroll
        for (int j = 0; j < 8; ++j) {
            const float v = dd[rr][j];
            mA = fmaxf(mA, v);
            mF = fmaxf(mF, v < INF ? v : 0.0f);
        }
    #pragma unroll
    for (int o = 32; o > 0; o >>= 1) {
        mF = fmaxf(mF, __shfl_xor(mF, o));
        mA = fmaxf(mA, __shfl_xor(mA, o));
    }
    if ((t & 63) == 0) {
        lds[RED + ((t >> 6) << 1)]     = mF;
        lds[RED + ((t >> 6) << 1) + 1] = mA;
    }
    __syncthreads();
    mF = lds[RED]; mA = lds[RED + 1];
    #pragma unroll
    for (int wv = 1; wv < 8; ++wv) {
        mF = fmaxf(mF, lds[RED + wv*2]);
        mA = fmaxf(mA, lds[RED + wv*2 + 1]);
    }
    const float twoF  = 2.0f * mF;
    const float maxv  = fmaxf((mA == INF) ? twoF : mF, 1e-8f);
    const float nscal = -SCALE_F / maxv;

    // ---- normalize in registers, store 8 heads (coalesced, nontemporal) ----
    float* const outg = out + (size_t)g * (NHEADS * NCELL);
    #pragma unroll
    for (int rr = 0; rr < 4; ++rr) {
        const int i = (rgrp << 2) + rr;
        #pragma unroll
        for (int c = 0; c < 2; ++c) {
            nfloat4 v;
            v.x = ((dd[rr][c*4+0] == INF) ? twoF : dd[rr][c*4+0]) * nscal;
            v.y = ((dd[rr][c*4+1] == INF) ? twoF : dd[rr][c*4+1]) * nscal;
            v.z = ((dd[rr][c*4+2] == INF) ? twoF : dd[rr][c*4+2]) * nscal;
            v.w = ((dd[rr][c*4+3] == INF) ? twoF : dd[rr][c*4+3]) * nscal;
            const int o = (i << 7) + (cgrp << 2) + (c << 6);
            #pragma unroll
            for (int h = 0; h < NHEADS; ++h) {
                __builtin_nontemporal_store(
                    v, reinterpret_cast<nfloat4*>(&outg[h * NCELL + o]));
            }
        }
    }
}

extern "C" void kernel_launch(void* const* d_in, const int* in_sizes, int n_in,
                              void* d_out, int out_size, void* d_ws, size_t ws_size,
                              hipStream_t stream)
{
    const int*   edge_index  = (const int*)d_in[0];
    const float* edge_w      = (const float*)d_in[1];
    const int E    = in_sizes[1];
    const int Ntot = in_sizes[2];
    const int G    = Ntot / NN;
    const int epg  = E / G;
    float* out = (float*)d_out;
    spb_fw_kernel<<<G, NT, 0, stream>>>(edge_index, edge_w, E, epg, out);
}